// Round 2
// 338.887 us; speedup vs baseline: 1.0051x; 1.0051x over previous
//
#include <hip/hip_runtime.h>

#define BB 4
#define SS 2048
#define DD 1024
#define HH 16
#define DHH 64

typedef _Float16 half8 __attribute__((ext_vector_type(8)));
typedef _Float16 half4v __attribute__((ext_vector_type(4)));
typedef _Float16 half2v __attribute__((ext_vector_type(2)));
typedef float floatx4 __attribute__((ext_vector_type(4)));

#define GLOBAL_AS __attribute__((address_space(1)))
#define LDS_AS __attribute__((address_space(3)))

// Q pre-scale: 1/sqrt(DH) * log2(e), so attn can use v_exp_f32 (exp2) directly.
#define QSCALE 0.18033688011112042f

// ---------------------------------------------------------------------------
// Weight transpose + fp32->f16 convert: wt[n*1024+k] = (f16) w[k*1024+n]
// z: 0=Wq 1=Wk 2=Wv 3=Wo. grid (32, 32, 4), block 256
// ---------------------------------------------------------------------------
__global__ void wt_kernel(const float* __restrict__ w0, const float* __restrict__ w1,
                          const float* __restrict__ w2, const float* __restrict__ w3,
                          _Float16* __restrict__ wt) {
  __shared__ float tile[32][33];
  int z = blockIdx.z;
  const float* w = (z == 0) ? w0 : (z == 1) ? w1 : (z == 2) ? w2 : w3;
  _Float16* dst = wt + (size_t)z * 1024 * 1024;
  int k0 = blockIdx.x * 32, n0 = blockIdx.y * 32;
  int tx = threadIdx.x & 31, ty = threadIdx.x >> 5;  // ty 0..7
#pragma unroll
  for (int r = ty; r < 32; r += 8) tile[r][tx] = w[(size_t)(k0 + r) * 1024 + n0 + tx];
  __syncthreads();
#pragma unroll
  for (int r = ty; r < 32; r += 8) dst[(size_t)(n0 + r) * 1024 + k0 + tx] = (_Float16)tile[tx][r];
}

// ---------------------------------------------------------------------------
// fp32 -> f16 convert of q,k,v into concatenated Acat [3 x 8192 x 1024].
// grid (4096, 3), block 256, 8 elems/thread.
// ---------------------------------------------------------------------------
__global__ void cvt3_kernel(const float* __restrict__ q, const float* __restrict__ k,
                            const float* __restrict__ v, _Float16* __restrict__ dst) {
  int z = blockIdx.y;
  const float* src = (z == 0) ? q : (z == 1) ? k : v;
  size_t i = ((size_t)blockIdx.x * 256 + threadIdx.x) * 8;
  float4 f0 = *(const float4*)(src + i);
  float4 f1 = *(const float4*)(src + i + 4);
  half8 h = {(_Float16)f0.x, (_Float16)f0.y, (_Float16)f0.z, (_Float16)f0.w,
             (_Float16)f1.x, (_Float16)f1.y, (_Float16)f1.z, (_Float16)f1.w};
  *(half8*)(dst + (size_t)z * 8388608 + i) = h;
}

// ---------------------------------------------------------------------------
// Fused QKV projection GEMM: C[24576, 1024] block-diagonal over 3 weights.
// grid (8, 192): proj = bm>>6 selects Wq/Wk/Wv and the output routing:
//   proj 0 -> Qf f16 row-major, scaled by QSCALE = 0.125*log2(e)
//   proj 1 -> Kf f16 row-major
//   proj 2 -> Vt f16 transposed: Vt[(b*1024+n)*2048+s]
// ---------------------------------------------------------------------------
__global__ __launch_bounds__(256) void qkv_gemm(const _Float16* __restrict__ Acat,
                                                const _Float16* __restrict__ Wt,
                                                _Float16* __restrict__ Qf,
                                                _Float16* __restrict__ Kf,
                                                _Float16* __restrict__ Vt) {
  __shared__ _Float16 lA[128 * 32];
  __shared__ _Float16 lB[128 * 32];
  int tid = threadIdx.x;
  int wave = tid >> 6, lane = tid & 63, quad = lane >> 4, l15 = lane & 15;
  int bn = blockIdx.x, bm = blockIdx.y;
  int proj = bm >> 6;
  int wm = wave >> 1, wn = wave & 1;

  const _Float16* A = Acat + (size_t)bm * 128 * 1024;
  const _Float16* W = Wt + (size_t)proj * 1024 * 1024;

  floatx4 fzero = {0.f, 0.f, 0.f, 0.f};
  floatx4 acc[4][4];
#pragma unroll
  for (int i = 0; i < 4; ++i)
#pragma unroll
    for (int j = 0; j < 4; ++j) acc[i][j] = fzero;

  int g0 = tid, g1 = 256 + tid;
  int row0 = g0 >> 2, gc0 = (g0 & 3) ^ ((row0 >> 1) & 3);
  int row1 = g1 >> 2, gc1 = (g1 & 3) ^ ((row1 >> 1) & 3);
  const _Float16* a0 = A + ((size_t)row0 * 1024 + gc0 * 8);
  const _Float16* a1 = A + ((size_t)row1 * 1024 + gc1 * 8);
  const _Float16* b0 = W + ((size_t)(bn * 128 + row0) * 1024 + gc0 * 8);
  const _Float16* b1 = W + ((size_t)(bn * 128 + row1) * 1024 + gc1 * 8);

  for (int k0 = 0; k0 < 1024; k0 += 32) {
    __builtin_amdgcn_global_load_lds((const GLOBAL_AS void*)(a0 + k0),
                                     (LDS_AS void*)(lA + g0 * 8), 16, 0, 0);
    __builtin_amdgcn_global_load_lds((const GLOBAL_AS void*)(a1 + k0),
                                     (LDS_AS void*)(lA + g1 * 8), 16, 0, 0);
    __builtin_amdgcn_global_load_lds((const GLOBAL_AS void*)(b0 + k0),
                                     (LDS_AS void*)(lB + g0 * 8), 16, 0, 0);
    __builtin_amdgcn_global_load_lds((const GLOBAL_AS void*)(b1 + k0),
                                     (LDS_AS void*)(lB + g1 * 8), 16, 0, 0);
    __syncthreads();

    half8 af[4], bf[4];
#pragma unroll
    for (int i = 0; i < 4; ++i) {
      int row = wm * 64 + i * 16 + l15;
      af[i] = *(const half8*)(lA + (row * 4 + (quad ^ ((row >> 1) & 3))) * 8);
    }
#pragma unroll
    for (int j = 0; j < 4; ++j) {
      int row = wn * 64 + j * 16 + l15;
      bf[j] = *(const half8*)(lB + (row * 4 + (quad ^ ((row >> 1) & 3))) * 8);
    }
#pragma unroll
    for (int i = 0; i < 4; ++i)
#pragma unroll
      for (int j = 0; j < 4; ++j)
        acc[i][j] = __builtin_amdgcn_mfma_f32_16x16x32_f16(af[i], bf[j], acc[i][j], 0, 0, 0);
    __syncthreads();
  }

  // ---- epilogue (block-uniform proj branch) ----
  int rloc = (bm & 63) * 128;  // row within this projection's [8192,1024] output
#pragma unroll
  for (int i = 0; i < 4; ++i) {
#pragma unroll
    for (int j = 0; j < 4; ++j) {
      int rowb = rloc + wm * 64 + i * 16 + quad * 4;
      int col = bn * 128 + wn * 64 + j * 16 + l15;
      if (proj == 0) {
#pragma unroll
        for (int r = 0; r < 4; ++r)
          Qf[(size_t)(rowb + r) * 1024 + col] = (_Float16)(acc[i][j][r] * QSCALE);
      } else if (proj == 1) {
#pragma unroll
        for (int r = 0; r < 4; ++r)
          Kf[(size_t)(rowb + r) * 1024 + col] = (_Float16)acc[i][j][r];
      } else {
        int b = rowb >> 11, s = rowb & 2047;
        half4v pk = {(_Float16)acc[i][j][0], (_Float16)acc[i][j][1],
                     (_Float16)acc[i][j][2], (_Float16)acc[i][j][3]};
        *(half4v*)(Vt + (size_t)(b * 1024 + col) * 2048 + s) = pk;
      }
    }
  }
}

// ---------------------------------------------------------------------------
// Final GEMM: d_out[8192,1024] = Of[8192,1024] @ Wo^T  (fp32 out)
// ---------------------------------------------------------------------------
__global__ __launch_bounds__(256) void gemm_out(const _Float16* __restrict__ A,
                                                const _Float16* __restrict__ Wt,
                                                float* __restrict__ C) {
  __shared__ _Float16 lA[128 * 32];
  __shared__ _Float16 lB[128 * 32];
  int tid = threadIdx.x;
  int wave = tid >> 6, lane = tid & 63, quad = lane >> 4, l15 = lane & 15;
  int bn = blockIdx.x, bm = blockIdx.y;
  int wm = wave >> 1, wn = wave & 1;

  floatx4 fzero = {0.f, 0.f, 0.f, 0.f};
  floatx4 acc[4][4];
#pragma unroll
  for (int i = 0; i < 4; ++i)
#pragma unroll
    for (int j = 0; j < 4; ++j) acc[i][j] = fzero;

  int g0 = tid, g1 = 256 + tid;
  int row0 = g0 >> 2, gc0 = (g0 & 3) ^ ((row0 >> 1) & 3);
  int row1 = g1 >> 2, gc1 = (g1 & 3) ^ ((row1 >> 1) & 3);
  const _Float16* a0 = A + ((size_t)(bm * 128 + row0) * 1024 + gc0 * 8);
  const _Float16* a1 = A + ((size_t)(bm * 128 + row1) * 1024 + gc1 * 8);
  const _Float16* b0 = Wt + ((size_t)(bn * 128 + row0) * 1024 + gc0 * 8);
  const _Float16* b1 = Wt + ((size_t)(bn * 128 + row1) * 1024 + gc1 * 8);

  for (int k0 = 0; k0 < 1024; k0 += 32) {
    __builtin_amdgcn_global_load_lds((const GLOBAL_AS void*)(a0 + k0),
                                     (LDS_AS void*)(lA + g0 * 8), 16, 0, 0);
    __builtin_amdgcn_global_load_lds((const GLOBAL_AS void*)(a1 + k0),
                                     (LDS_AS void*)(lA + g1 * 8), 16, 0, 0);
    __builtin_amdgcn_global_load_lds((const GLOBAL_AS void*)(b0 + k0),
                                     (LDS_AS void*)(lB + g0 * 8), 16, 0, 0);
    __builtin_amdgcn_global_load_lds((const GLOBAL_AS void*)(b1 + k0),
                                     (LDS_AS void*)(lB + g1 * 8), 16, 0, 0);
    __syncthreads();

    half8 af[4], bf[4];
#pragma unroll
    for (int i = 0; i < 4; ++i) {
      int row = wm * 64 + i * 16 + l15;
      af[i] = *(const half8*)(lA + (row * 4 + (quad ^ ((row >> 1) & 3))) * 8);
    }
#pragma unroll
    for (int j = 0; j < 4; ++j) {
      int row = wn * 64 + j * 16 + l15;
      bf[j] = *(const half8*)(lB + (row * 4 + (quad ^ ((row >> 1) & 3))) * 8);
    }
#pragma unroll
    for (int i = 0; i < 4; ++i)
#pragma unroll
      for (int j = 0; j < 4; ++j)
        acc[i][j] = __builtin_amdgcn_mfma_f32_16x16x32_f16(af[i], bf[j], acc[i][j], 0, 0, 0);
    __syncthreads();
  }

#pragma unroll
  for (int i = 0; i < 4; ++i)
#pragma unroll
    for (int j = 0; j < 4; ++j) {
      int rowb = bm * 128 + wm * 64 + i * 16 + quad * 4;
      int col = bn * 128 + wn * 64 + j * 16 + l15;
#pragma unroll
      for (int r = 0; r < 4; ++r) C[(size_t)(rowb + r) * 1024 + col] = acc[i][j][r];
    }
}

// ---------------------------------------------------------------------------
// Flash attention, STATIC-MAX softmax, SWAPPED QK^T.
// sacc = mfma(K, Q): C[row=key quad*4+r][col=qrow l15]. Each lane owns ONE
// q-row (l15) x 16 keys contiguous in r -> P packs to ds_write_b64 (4/chunk),
// PV A-frag is a contiguous ds_read_b128 (2/chunk). 8B-granule XOR swizzle
// (g ^= (l15&7)<<1) keeps both at the bank-throughput minimum.
// Q is pre-scaled by 0.125*log2(e) so p = v_exp_f32(s) directly.
// Masking: vlen is BLOCK-uniform -> scalar `clean` branch skips all cndmasks
// on full chunks. exp2(-1e6)=0 handles masked keys; vlen==0 -> mask 0 ->
// p=1 uniform (= reference). Row-sum l: ONE scalar/lane, reduced over quads
// (xor 16,32) once at the end; 1/l redistributed with 4 epilogue shuffles.
// grid (32, 64) block 256
// ---------------------------------------------------------------------------
__global__ __launch_bounds__(256) void attn_kernel(const _Float16* __restrict__ Q,
                                                   const _Float16* __restrict__ K,
                                                   const _Float16* __restrict__ Vt,
                                                   const int* __restrict__ vlens,
                                                   _Float16* __restrict__ O) {
  __shared__ _Float16 lK[64 * 64];      // [key][dh], swizzled
  __shared__ _Float16 lV[64 * 64];      // [dh][key], swizzled
  __shared__ _Float16 lP[4 * 16 * 64];  // per-wave [qrow][key], granule-swizzled

  int tid = threadIdx.x, wave = tid >> 6, lane = tid & 63, quad = lane >> 4, l15 = lane & 15;
  int bh = blockIdx.y, b = bh >> 4, h = bh & 15;
  int q0 = blockIdx.x * 64;
  int vlen = vlens[b];
  int nch = (vlen == 0) ? (SS / 64) : ((vlen + 63) >> 6);
  float mask_val = (vlen == 0) ? 0.0f : -1.0e6f;

  const _Float16* qb = Q + ((size_t)(b * SS + q0 + wave * 16 + l15) * DD + h * 64 + quad * 8);
  half8 qf0 = *(const half8*)qb;
  half8 qf1 = *(const half8*)(qb + 32);

  // ---- hoisted, kc-invariant LDS offsets (halves) ----
  int off[2][4];  // lK / lV fragment reads (same swizzle both)
#pragma unroll
  for (int ks = 0; ks < 2; ++ks)
#pragma unroll
    for (int j = 0; j < 4; ++j) {
      int row = j * 16 + l15, gc = ks * 4 + quad;
      off[ks][j] = (row * 8 + (gc ^ (row & 7))) * 8;
    }
  int m = (l15 & 7) << 1;
  int pbase = wave * 1024 + l15 * 64;
  int wp[4], rp[2];
#pragma unroll
  for (int j = 0; j < 4; ++j) wp[j] = pbase + (((j * 4 + quad) ^ m) << 2);
#pragma unroll
  for (int ks = 0; ks < 2; ++ks) rp[ks] = pbase + (((ks * 8 + quad * 2) ^ m) << 2);

  float l_acc = 0.f;
  floatx4 fzero = {0.f, 0.f, 0.f, 0.f};
  floatx4 o[4];
#pragma unroll
  for (int j = 0; j < 4; ++j) o[j] = fzero;

  for (int kc = 0; kc < nch; ++kc) {
    int kb = kc * 64;
    // ---- stage K chunk [64 keys][64 dh] and V^T chunk [64 dh][64 keys] ----
#pragma unroll
    for (int ss = tid; ss < 512; ss += 256) {
      int row = ss >> 3, gc = ss & 7;
      int sidx = (row * 8 + (gc ^ (row & 7))) * 8;
      *(half8*)(lK + sidx) =
          *(const half8*)(K + ((size_t)(b * SS + kb + row) * DD + h * 64 + gc * 8));
      *(half8*)(lV + sidx) =
          *(const half8*)(Vt + ((size_t)(b * DD + h * 64 + row) * SS + kb + gc * 8));
    }
    __syncthreads();

    // ---- S^T = K Q^T (64 keys x 16 queries per wave) ----
    floatx4 sacc[4];
#pragma unroll
    for (int j = 0; j < 4; ++j) sacc[j] = fzero;
#pragma unroll
    for (int ks = 0; ks < 2; ++ks) {
      half8 qf = ks ? qf1 : qf0;
#pragma unroll
      for (int j = 0; j < 4; ++j) {
        half8 kf = *(const half8*)(lK + off[ks][j]);
        sacc[j] = __builtin_amdgcn_mfma_f32_16x16x32_f16(kf, qf, sacc[j], 0, 0, 0);
      }
    }

    // ---- exp2 (mask branch is wave-uniform) ----
    float p[4][4];
    if (kb + 64 <= vlen) {
#pragma unroll
      for (int j = 0; j < 4; ++j)
#pragma unroll
        for (int r = 0; r < 4; ++r) p[j][r] = __builtin_amdgcn_exp2f(sacc[j][r]);
    } else {
#pragma unroll
      for (int j = 0; j < 4; ++j)
#pragma unroll
        for (int r = 0; r < 4; ++r) {
          int key = kb + j * 16 + quad * 4 + r;
          float s = (key < vlen) ? sacc[j][r] : mask_val;
          p[j][r] = __builtin_amdgcn_exp2f(s);
        }
    }

    // ---- row-sum + packed P write (b64 per j, keys contiguous in r) ----
#pragma unroll
    for (int j = 0; j < 4; ++j) {
      l_acc += (p[j][0] + p[j][1]) + (p[j][2] + p[j][3]);
      half2v lo = __builtin_bit_cast(half2v, __builtin_amdgcn_cvt_pkrtz(p[j][0], p[j][1]));
      half2v hi = __builtin_bit_cast(half2v, __builtin_amdgcn_cvt_pkrtz(p[j][2], p[j][3]));
      half4v w4 = {lo.x, lo.y, hi.x, hi.y};
      *(half4v*)(lP + wp[j]) = w4;
    }

    // ---- O += P V (in-wave lP write->read ordered by lgkmcnt, no barrier) ----
#pragma unroll
    for (int ks = 0; ks < 2; ++ks) {
      half8 pf = *(const half8*)(lP + rp[ks]);
#pragma unroll
      for (int j = 0; j < 4; ++j) {
        half8 vf = *(const half8*)(lV + off[ks][j]);
        o[j] = __builtin_amdgcn_mfma_f32_16x16x32_f16(pf, vf, o[j], 0, 0, 0);
      }
    }
    __syncthreads();  // protect lK/lV before next chunk staging
  }

  // ---- epilogue: reduce l over quads, redistribute 1/l, write O ----
  float l = l_acc;
  l += __shfl_xor(l, 16);
  l += __shfl_xor(l, 32);
  float inv = 1.0f / l;
  float inv_r[4];
#pragma unroll
  for (int r = 0; r < 4; ++r) inv_r[r] = __shfl(inv, quad * 4 + r);
#pragma unroll
  for (int j = 0; j < 4; ++j) {
    int col = h * 64 + j * 16 + l15;
#pragma unroll
    for (int r = 0; r < 4; ++r) {
      int qrow = q0 + wave * 16 + quad * 4 + r;
      O[(size_t)(b * SS + qrow) * DD + col] = (_Float16)(o[j][r] * inv_r[r]);
    }
  }
}

// ---------------------------------------------------------------------------
extern "C" void kernel_launch(void* const* d_in, const int* in_sizes, int n_in,
                              void* d_out, int out_size, void* d_ws, size_t ws_size,
                              hipStream_t stream) {
  const float* q = (const float*)d_in[0];
  const float* k = (const float*)d_in[1];
  const float* v = (const float*)d_in[2];
  const int* vl = (const int*)d_in[3];
  const float* wq = (const float*)d_in[4];
  const float* wk = (const float*)d_in[5];
  const float* wv = (const float*)d_in[6];
  const float* wo = (const float*)d_in[7];

  char* ws = (char*)d_ws;
  _Float16* Wt = (_Float16*)ws;                        // 4 x 1M f16  = 8 MB
  _Float16* Acat = (_Float16*)(ws + (8u << 20));       // 48 MB [3 x 8192 x 1024]
  _Float16* Qf = (_Float16*)(ws + (56u << 20));        // 16 MB
  _Float16* Kf = (_Float16*)(ws + (72u << 20));        // 16 MB
  _Float16* Vt = (_Float16*)(ws + (88u << 20));        // 16 MB [B, D, S] (104 MB total)
  _Float16* Of = Acat;                                  // Acat dead after qkv_gemm

  dim3 blk(256);

  wt_kernel<<<dim3(32, 32, 4), blk, 0, stream>>>(wq, wk, wv, wo, Wt);
  cvt3_kernel<<<dim3(4096, 3), blk, 0, stream>>>(q, k, v, Acat);
  qkv_gemm<<<dim3(8, 192), blk, 0, stream>>>(Acat, Wt, Qf, Kf, Vt);
  attn_kernel<<<dim3(32, 64), blk, 0, stream>>>(Qf, Kf, Vt, vl, Of);
  gemm_out<<<dim3(8, 64), blk, 0, stream>>>(Of, Wt + (3u << 20), (float*)d_out);
}

// Round 3
// 336.902 us; speedup vs baseline: 1.0111x; 1.0059x over previous
//
#include <hip/hip_runtime.h>

#define BB 4
#define SS 2048
#define DD 1024
#define HH 16
#define DHH 64

typedef _Float16 half8 __attribute__((ext_vector_type(8)));
typedef _Float16 half4v __attribute__((ext_vector_type(4)));
typedef _Float16 half2v __attribute__((ext_vector_type(2)));
typedef float floatx4 __attribute__((ext_vector_type(4)));

#define GLOBAL_AS __attribute__((address_space(1)))
#define LDS_AS __attribute__((address_space(3)))

// Q pre-scale: 1/sqrt(DH) * log2(e), so attn can use v_exp_f32 (exp2) directly.
#define QSCALE 0.18033688011112042f

// ---------------------------------------------------------------------------
// Weight transpose + fp32->f16 convert: wt[n*1024+k] = (f16) w[k*1024+n]
// z: 0=Wq 1=Wk 2=Wv 3=Wo. grid (32, 32, 4), block 256
// ---------------------------------------------------------------------------
__global__ void wt_kernel(const float* __restrict__ w0, const float* __restrict__ w1,
                          const float* __restrict__ w2, const float* __restrict__ w3,
                          _Float16* __restrict__ wt) {
  __shared__ float tile[32][33];
  int z = blockIdx.z;
  const float* w = (z == 0) ? w0 : (z == 1) ? w1 : (z == 2) ? w2 : w3;
  _Float16* dst = wt + (size_t)z * 1024 * 1024;
  int k0 = blockIdx.x * 32, n0 = blockIdx.y * 32;
  int tx = threadIdx.x & 31, ty = threadIdx.x >> 5;  // ty 0..7
#pragma unroll
  for (int r = ty; r < 32; r += 8) tile[r][tx] = w[(size_t)(k0 + r) * 1024 + n0 + tx];
  __syncthreads();
#pragma unroll
  for (int r = ty; r < 32; r += 8) dst[(size_t)(n0 + r) * 1024 + k0 + tx] = (_Float16)tile[tx][r];
}

// ---------------------------------------------------------------------------
// fp32 -> f16 convert of q,k,v into concatenated Acat [3 x 8192 x 1024].
// grid (4096, 3), block 256, 8 elems/thread.
// ---------------------------------------------------------------------------
__global__ void cvt3_kernel(const float* __restrict__ q, const float* __restrict__ k,
                            const float* __restrict__ v, _Float16* __restrict__ dst) {
  int z = blockIdx.y;
  const float* src = (z == 0) ? q : (z == 1) ? k : v;
  size_t i = ((size_t)blockIdx.x * 256 + threadIdx.x) * 8;
  float4 f0 = *(const float4*)(src + i);
  float4 f1 = *(const float4*)(src + i + 4);
  half8 h = {(_Float16)f0.x, (_Float16)f0.y, (_Float16)f0.z, (_Float16)f0.w,
             (_Float16)f1.x, (_Float16)f1.y, (_Float16)f1.z, (_Float16)f1.w};
  *(half8*)(dst + (size_t)z * 8388608 + i) = h;
}

// ---------------------------------------------------------------------------
// Fused QKV projection GEMM: C[24576, 1024] block-diagonal over 3 weights.
// grid (8, 192) XCD-swizzled: proj = bm>>6 selects Wq/Wk/Wv, output routing:
//   proj 0 -> Qf f16 row-major, scaled by QSCALE = 0.125*log2(e)
//   proj 1 -> Kf f16 row-major
//   proj 2 -> Vt f16 transposed: Vt[(b*1024+n)*2048+s]
// XCD swizzle (T1): dispatch round-robins linear wgid over 8 XCDs; remap so
// each XCD gets 192 consecutive swz = 24 full bm panels -> A panel fetched
// into ONE XCD L2 instead of all 8 (A re-fetch 8x -> 1x).
// ---------------------------------------------------------------------------
__global__ __launch_bounds__(256) void qkv_gemm(const _Float16* __restrict__ Acat,
                                                const _Float16* __restrict__ Wt,
                                                _Float16* __restrict__ Qf,
                                                _Float16* __restrict__ Kf,
                                                _Float16* __restrict__ Vt) {
  __shared__ _Float16 lA[128 * 32];
  __shared__ _Float16 lB[128 * 32];
  int tid = threadIdx.x;
  int wave = tid >> 6, lane = tid & 63, quad = lane >> 4, l15 = lane & 15;
  int wgid = blockIdx.y * 8 + blockIdx.x;          // nwg = 1536
  int swz = (wgid & 7) * 192 + (wgid >> 3);        // bijective (1536 % 8 == 0)
  int bn = swz & 7, bm = swz >> 3;
  int proj = bm >> 6;
  int wm = wave >> 1, wn = wave & 1;

  const _Float16* A = Acat + (size_t)bm * 128 * 1024;
  const _Float16* W = Wt + (size_t)proj * 1024 * 1024;

  floatx4 fzero = {0.f, 0.f, 0.f, 0.f};
  floatx4 acc[4][4];
#pragma unroll
  for (int i = 0; i < 4; ++i)
#pragma unroll
    for (int j = 0; j < 4; ++j) acc[i][j] = fzero;

  int g0 = tid, g1 = 256 + tid;
  int row0 = g0 >> 2, gc0 = (g0 & 3) ^ ((row0 >> 1) & 3);
  int row1 = g1 >> 2, gc1 = (g1 & 3) ^ ((row1 >> 1) & 3);
  const _Float16* a0 = A + ((size_t)row0 * 1024 + gc0 * 8);
  const _Float16* a1 = A + ((size_t)row1 * 1024 + gc1 * 8);
  const _Float16* b0 = W + ((size_t)(bn * 128 + row0) * 1024 + gc0 * 8);
  const _Float16* b1 = W + ((size_t)(bn * 128 + row1) * 1024 + gc1 * 8);

  for (int k0 = 0; k0 < 1024; k0 += 32) {
    __builtin_amdgcn_global_load_lds((const GLOBAL_AS void*)(a0 + k0),
                                     (LDS_AS void*)(lA + g0 * 8), 16, 0, 0);
    __builtin_amdgcn_global_load_lds((const GLOBAL_AS void*)(a1 + k0),
                                     (LDS_AS void*)(lA + g1 * 8), 16, 0, 0);
    __builtin_amdgcn_global_load_lds((const GLOBAL_AS void*)(b0 + k0),
                                     (LDS_AS void*)(lB + g0 * 8), 16, 0, 0);
    __builtin_amdgcn_global_load_lds((const GLOBAL_AS void*)(b1 + k0),
                                     (LDS_AS void*)(lB + g1 * 8), 16, 0, 0);
    __syncthreads();

    half8 af[4], bf[4];
#pragma unroll
    for (int i = 0; i < 4; ++i) {
      int row = wm * 64 + i * 16 + l15;
      af[i] = *(const half8*)(lA + (row * 4 + (quad ^ ((row >> 1) & 3))) * 8);
    }
#pragma unroll
    for (int j = 0; j < 4; ++j) {
      int row = wn * 64 + j * 16 + l15;
      bf[j] = *(const half8*)(lB + (row * 4 + (quad ^ ((row >> 1) & 3))) * 8);
    }
#pragma unroll
    for (int i = 0; i < 4; ++i)
#pragma unroll
      for (int j = 0; j < 4; ++j)
        acc[i][j] = __builtin_amdgcn_mfma_f32_16x16x32_f16(af[i], bf[j], acc[i][j], 0, 0, 0);
    __syncthreads();
  }

  // ---- epilogue (block-uniform proj branch) ----
  int rloc = (bm & 63) * 128;  // row within this projection's [8192,1024] output
#pragma unroll
  for (int i = 0; i < 4; ++i) {
#pragma unroll
    for (int j = 0; j < 4; ++j) {
      int rowb = rloc + wm * 64 + i * 16 + quad * 4;
      int col = bn * 128 + wn * 64 + j * 16 + l15;
      if (proj == 0) {
#pragma unroll
        for (int r = 0; r < 4; ++r)
          Qf[(size_t)(rowb + r) * 1024 + col] = (_Float16)(acc[i][j][r] * QSCALE);
      } else if (proj == 1) {
#pragma unroll
        for (int r = 0; r < 4; ++r)
          Kf[(size_t)(rowb + r) * 1024 + col] = (_Float16)acc[i][j][r];
      } else {
        int b = rowb >> 11, s = rowb & 2047;
        half4v pk = {(_Float16)acc[i][j][0], (_Float16)acc[i][j][1],
                     (_Float16)acc[i][j][2], (_Float16)acc[i][j][3]};
        *(half4v*)(Vt + (size_t)(b * 1024 + col) * 2048 + s) = pk;
      }
    }
  }
}

// ---------------------------------------------------------------------------
// Final GEMM: d_out[8192,1024] = Of[8192,1024] @ Wo^T  (fp32 out)
// XCD-swizzled (nwg = 512, 512 % 8 == 0).
// ---------------------------------------------------------------------------
__global__ __launch_bounds__(256) void gemm_out(const _Float16* __restrict__ A,
                                                const _Float16* __restrict__ Wt,
                                                float* __restrict__ C) {
  __shared__ _Float16 lA[128 * 32];
  __shared__ _Float16 lB[128 * 32];
  int tid = threadIdx.x;
  int wave = tid >> 6, lane = tid & 63, quad = lane >> 4, l15 = lane & 15;
  int wgid = blockIdx.y * 8 + blockIdx.x;          // nwg = 512
  int swz = (wgid & 7) * 64 + (wgid >> 3);
  int bn = swz & 7, bm = swz >> 3;
  int wm = wave >> 1, wn = wave & 1;

  floatx4 fzero = {0.f, 0.f, 0.f, 0.f};
  floatx4 acc[4][4];
#pragma unroll
  for (int i = 0; i < 4; ++i)
#pragma unroll
    for (int j = 0; j < 4; ++j) acc[i][j] = fzero;

  int g0 = tid, g1 = 256 + tid;
  int row0 = g0 >> 2, gc0 = (g0 & 3) ^ ((row0 >> 1) & 3);
  int row1 = g1 >> 2, gc1 = (g1 & 3) ^ ((row1 >> 1) & 3);
  const _Float16* a0 = A + ((size_t)(bm * 128 + row0) * 1024 + gc0 * 8);
  const _Float16* a1 = A + ((size_t)(bm * 128 + row1) * 1024 + gc1 * 8);
  const _Float16* b0 = Wt + ((size_t)(bn * 128 + row0) * 1024 + gc0 * 8);
  const _Float16* b1 = Wt + ((size_t)(bn * 128 + row1) * 1024 + gc1 * 8);

  for (int k0 = 0; k0 < 1024; k0 += 32) {
    __builtin_amdgcn_global_load_lds((const GLOBAL_AS void*)(a0 + k0),
                                     (LDS_AS void*)(lA + g0 * 8), 16, 0, 0);
    __builtin_amdgcn_global_load_lds((const GLOBAL_AS void*)(a1 + k0),
                                     (LDS_AS void*)(lA + g1 * 8), 16, 0, 0);
    __builtin_amdgcn_global_load_lds((const GLOBAL_AS void*)(b0 + k0),
                                     (LDS_AS void*)(lB + g0 * 8), 16, 0, 0);
    __builtin_amdgcn_global_load_lds((const GLOBAL_AS void*)(b1 + k0),
                                     (LDS_AS void*)(lB + g1 * 8), 16, 0, 0);
    __syncthreads();

    half8 af[4], bf[4];
#pragma unroll
    for (int i = 0; i < 4; ++i) {
      int row = wm * 64 + i * 16 + l15;
      af[i] = *(const half8*)(lA + (row * 4 + (quad ^ ((row >> 1) & 3))) * 8);
    }
#pragma unroll
    for (int j = 0; j < 4; ++j) {
      int row = wn * 64 + j * 16 + l15;
      bf[j] = *(const half8*)(lB + (row * 4 + (quad ^ ((row >> 1) & 3))) * 8);
    }
#pragma unroll
    for (int i = 0; i < 4; ++i)
#pragma unroll
      for (int j = 0; j < 4; ++j)
        acc[i][j] = __builtin_amdgcn_mfma_f32_16x16x32_f16(af[i], bf[j], acc[i][j], 0, 0, 0);
    __syncthreads();
  }

#pragma unroll
  for (int i = 0; i < 4; ++i)
#pragma unroll
    for (int j = 0; j < 4; ++j) {
      int rowb = bm * 128 + wm * 64 + i * 16 + quad * 4;
      int col = bn * 128 + wn * 64 + j * 16 + l15;
#pragma unroll
      for (int r = 0; r < 4; ++r) C[(size_t)(rowb + r) * 1024 + col] = acc[i][j][r];
    }
}

// ---------------------------------------------------------------------------
// Flash attention, STATIC-MAX softmax, SWAPPED QK^T.
// sacc = mfma(K, Q): each lane owns ONE q-row (l15) x 16 keys contiguous in r.
// lP layout: per-wave rows of 16 granules (4 halves = 8B each); granule g of
// row l15 stored at position g ^ l15 (FULL 4-bit XOR). For fixed (j,quad),
// the 16 lanes of a write phase cover all 16 positions = all 32 banks exactly
// once -> conflict-free b64 writes. The pf read must preserve key order, and
// (g^l15) flips bit0 for odd rows, so read as TWO ds_read_b64 at positions
// (gl)^l15 and (gl+1)^l15, assembled in registers (conflict-free per phase).
// T5: setprio(1) around both MFMA clusters.
// grid (32, 64) block 256
// ---------------------------------------------------------------------------
__global__ __launch_bounds__(256) void attn_kernel(const _Float16* __restrict__ Q,
                                                   const _Float16* __restrict__ K,
                                                   const _Float16* __restrict__ Vt,
                                                   const int* __restrict__ vlens,
                                                   _Float16* __restrict__ O) {
  __shared__ _Float16 lK[64 * 64];      // [key][dh], swizzled
  __shared__ _Float16 lV[64 * 64];      // [dh][key], swizzled
  __shared__ _Float16 lP[4 * 16 * 64];  // per-wave [qrow][key], granule-swizzled

  int tid = threadIdx.x, wave = tid >> 6, lane = tid & 63, quad = lane >> 4, l15 = lane & 15;
  int bh = blockIdx.y, b = bh >> 4, h = bh & 15;
  int q0 = blockIdx.x * 64;
  int vlen = vlens[b];
  int nch = (vlen == 0) ? (SS / 64) : ((vlen + 63) >> 6);
  float mask_val = (vlen == 0) ? 0.0f : -1.0e6f;

  const _Float16* qb = Q + ((size_t)(b * SS + q0 + wave * 16 + l15) * DD + h * 64 + quad * 8);
  half8 qf0 = *(const half8*)qb;
  half8 qf1 = *(const half8*)(qb + 32);

  // ---- hoisted, kc-invariant LDS offsets (halves) ----
  int off[2][4];  // lK / lV fragment reads (same swizzle both)
#pragma unroll
  for (int ks = 0; ks < 2; ++ks)
#pragma unroll
    for (int j = 0; j < 4; ++j) {
      int row = j * 16 + l15, gc = ks * 4 + quad;
      off[ks][j] = (row * 8 + (gc ^ (row & 7))) * 8;
    }
  int pbase = wave * 1024 + l15 * 64;
  int wp[4], rpl[2], rph[2];
#pragma unroll
  for (int j = 0; j < 4; ++j) wp[j] = pbase + (((j * 4 + quad) ^ l15) << 2);
#pragma unroll
  for (int ks = 0; ks < 2; ++ks) {
    int gl = ks * 8 + quad * 2;
    rpl[ks] = pbase + ((gl ^ l15) << 2);
    rph[ks] = pbase + (((gl + 1) ^ l15) << 2);
  }

  float l_acc = 0.f;
  floatx4 fzero = {0.f, 0.f, 0.f, 0.f};
  floatx4 o[4];
#pragma unroll
  for (int j = 0; j < 4; ++j) o[j] = fzero;

  for (int kc = 0; kc < nch; ++kc) {
    int kb = kc * 64;
    // ---- stage K chunk [64 keys][64 dh] and V^T chunk [64 dh][64 keys] ----
#pragma unroll
    for (int ss = tid; ss < 512; ss += 256) {
      int row = ss >> 3, gc = ss & 7;
      int sidx = (row * 8 + (gc ^ (row & 7))) * 8;
      *(half8*)(lK + sidx) =
          *(const half8*)(K + ((size_t)(b * SS + kb + row) * DD + h * 64 + gc * 8));
      *(half8*)(lV + sidx) =
          *(const half8*)(Vt + ((size_t)(b * DD + h * 64 + row) * SS + kb + gc * 8));
    }
    __syncthreads();

    // ---- S^T = K Q^T (64 keys x 16 queries per wave) ----
    floatx4 sacc[4];
#pragma unroll
    for (int j = 0; j < 4; ++j) sacc[j] = fzero;
    __builtin_amdgcn_s_setprio(1);
#pragma unroll
    for (int ks = 0; ks < 2; ++ks) {
      half8 qf = ks ? qf1 : qf0;
#pragma unroll
      for (int j = 0; j < 4; ++j) {
        half8 kf = *(const half8*)(lK + off[ks][j]);
        sacc[j] = __builtin_amdgcn_mfma_f32_16x16x32_f16(kf, qf, sacc[j], 0, 0, 0);
      }
    }
    __builtin_amdgcn_s_setprio(0);

    // ---- exp2 (mask branch is wave-uniform) ----
    float p[4][4];
    if (kb + 64 <= vlen) {
#pragma unroll
      for (int j = 0; j < 4; ++j)
#pragma unroll
        for (int r = 0; r < 4; ++r) p[j][r] = __builtin_amdgcn_exp2f(sacc[j][r]);
    } else {
#pragma unroll
      for (int j = 0; j < 4; ++j)
#pragma unroll
        for (int r = 0; r < 4; ++r) {
          int key = kb + j * 16 + quad * 4 + r;
          float s = (key < vlen) ? sacc[j][r] : mask_val;
          p[j][r] = __builtin_amdgcn_exp2f(s);
        }
    }

    // ---- row-sum + packed P write (b64 per j, keys contiguous in r) ----
#pragma unroll
    for (int j = 0; j < 4; ++j) {
      l_acc += (p[j][0] + p[j][1]) + (p[j][2] + p[j][3]);
      half2v lo = __builtin_bit_cast(half2v, __builtin_amdgcn_cvt_pkrtz(p[j][0], p[j][1]));
      half2v hi = __builtin_bit_cast(half2v, __builtin_amdgcn_cvt_pkrtz(p[j][2], p[j][3]));
      half4v w4 = {lo.x, lo.y, hi.x, hi.y};
      *(half4v*)(lP + wp[j]) = w4;
    }

    // ---- O += P V (in-wave lP write->read ordered by lgkmcnt, no barrier) ----
    __builtin_amdgcn_s_setprio(1);
#pragma unroll
    for (int ks = 0; ks < 2; ++ks) {
      half4v plo = *(const half4v*)(lP + rpl[ks]);
      half4v phi = *(const half4v*)(lP + rph[ks]);
      half8 pf = {plo.x, plo.y, plo.z, plo.w, phi.x, phi.y, phi.z, phi.w};
#pragma unroll
      for (int j = 0; j < 4; ++j) {
        half8 vf = *(const half8*)(lV + off[ks][j]);
        o[j] = __builtin_amdgcn_mfma_f32_16x16x32_f16(pf, vf, o[j], 0, 0, 0);
      }
    }
    __builtin_amdgcn_s_setprio(0);
    __syncthreads();  // protect lK/lV before next chunk staging
  }

  // ---- epilogue: reduce l over quads, redistribute 1/l, write O ----
  float l = l_acc;
  l += __shfl_xor(l, 16);
  l += __shfl_xor(l, 32);
  float inv = 1.0f / l;
  float inv_r[4];
#pragma unroll
  for (int r = 0; r < 4; ++r) inv_r[r] = __shfl(inv, quad * 4 + r);
#pragma unroll
  for (int j = 0; j < 4; ++j) {
    int col = h * 64 + j * 16 + l15;
#pragma unroll
    for (int r = 0; r < 4; ++r) {
      int qrow = q0 + wave * 16 + quad * 4 + r;
      O[(size_t)(b * SS + qrow) * DD + col] = (_Float16)(o[j][r] * inv_r[r]);
    }
  }
}

// ---------------------------------------------------------------------------
extern "C" void kernel_launch(void* const* d_in, const int* in_sizes, int n_in,
                              void* d_out, int out_size, void* d_ws, size_t ws_size,
                              hipStream_t stream) {
  const float* q = (const float*)d_in[0];
  const float* k = (const float*)d_in[1];
  const float* v = (const float*)d_in[2];
  const int* vl = (const int*)d_in[3];
  const float* wq = (const float*)d_in[4];
  const float* wk = (const float*)d_in[5];
  const float* wv = (const float*)d_in[6];
  const float* wo = (const float*)d_in[7];

  char* ws = (char*)d_ws;
  _Float16* Wt = (_Float16*)ws;                        // 4 x 1M f16  = 8 MB
  _Float16* Acat = (_Float16*)(ws + (8u << 20));       // 48 MB [3 x 8192 x 1024]
  _Float16* Qf = (_Float16*)(ws + (56u << 20));        // 16 MB
  _Float16* Kf = (_Float16*)(ws + (72u << 20));        // 16 MB
  _Float16* Vt = (_Float16*)(ws + (88u << 20));        // 16 MB [B, D, S] (104 MB total)
  _Float16* Of = Acat;                                  // Acat dead after qkv_gemm

  dim3 blk(256);

  wt_kernel<<<dim3(32, 32, 4), blk, 0, stream>>>(wq, wk, wv, wo, Wt);
  cvt3_kernel<<<dim3(4096, 3), blk, 0, stream>>>(q, k, v, Acat);
  qkv_gemm<<<dim3(8, 192), blk, 0, stream>>>(Acat, Wt, Qf, Kf, Vt);
  attn_kernel<<<dim3(32, 64), blk, 0, stream>>>(Qf, Kf, Vt, vl, Of);
  gemm_out<<<dim3(8, 64), blk, 0, stream>>>(Of, Wt + (3u << 20), (float*)d_out);
}

// Round 5
// 317.887 us; speedup vs baseline: 1.0715x; 1.0598x over previous
//
#include <hip/hip_runtime.h>

#define BB 4
#define SS 2048
#define DD 1024
#define HH 16
#define DHH 64

typedef _Float16 half8 __attribute__((ext_vector_type(8)));
typedef _Float16 half4v __attribute__((ext_vector_type(4)));
typedef _Float16 half2v __attribute__((ext_vector_type(2)));
typedef float floatx4 __attribute__((ext_vector_type(4)));

#define GLOBAL_AS __attribute__((address_space(1)))
#define LDS_AS __attribute__((address_space(3)))

// Q pre-scale: 1/sqrt(DH) * log2(e), so attn can use v_exp_f32 (exp2) directly.
#define QSCALE 0.18033688011112042f

// ---------------------------------------------------------------------------
// Weight transpose + fp32->f16 convert: wt[n*1024+k] = (f16) w[k*1024+n]
// z: 0=Wq 1=Wk 2=Wv 3=Wo. grid (32, 32, 4), block 256
// ---------------------------------------------------------------------------
__global__ void wt_kernel(const float* __restrict__ w0, const float* __restrict__ w1,
                          const float* __restrict__ w2, const float* __restrict__ w3,
                          _Float16* __restrict__ wt) {
  __shared__ float tile[32][33];
  int z = blockIdx.z;
  const float* w = (z == 0) ? w0 : (z == 1) ? w1 : (z == 2) ? w2 : w3;
  _Float16* dst = wt + (size_t)z * 1024 * 1024;
  int k0 = blockIdx.x * 32, n0 = blockIdx.y * 32;
  int tx = threadIdx.x & 31, ty = threadIdx.x >> 5;  // ty 0..7
#pragma unroll
  for (int r = ty; r < 32; r += 8) tile[r][tx] = w[(size_t)(k0 + r) * 1024 + n0 + tx];
  __syncthreads();
#pragma unroll
  for (int r = ty; r < 32; r += 8) dst[(size_t)(n0 + r) * 1024 + k0 + tx] = (_Float16)tile[tx][r];
}

// ---------------------------------------------------------------------------
// fp32 -> f16 convert of q,k,v into concatenated Acat [3 x 8192 x 1024].
// grid (4096, 3), block 256, 8 elems/thread.
// ---------------------------------------------------------------------------
__global__ void cvt3_kernel(const float* __restrict__ q, const float* __restrict__ k,
                            const float* __restrict__ v, _Float16* __restrict__ dst) {
  int z = blockIdx.y;
  const float* src = (z == 0) ? q : (z == 1) ? k : v;
  size_t i = ((size_t)blockIdx.x * 256 + threadIdx.x) * 8;
  float4 f0 = *(const float4*)(src + i);
  float4 f1 = *(const float4*)(src + i + 4);
  half8 h = {(_Float16)f0.x, (_Float16)f0.y, (_Float16)f0.z, (_Float16)f0.w,
             (_Float16)f1.x, (_Float16)f1.y, (_Float16)f1.z, (_Float16)f1.w};
  *(half8*)(dst + (size_t)z * 8388608 + i) = h;
}

// ---------------------------------------------------------------------------
// Fused QKV projection GEMM: C[24576, 1024] block-diagonal over 3 weights.
// grid (8, 192) XCD-swizzled: proj = bm>>6 selects Wq/Wk/Wv, output routing:
//   proj 0 -> Qf f16 row-major, scaled by QSCALE = 0.125*log2(e)
//   proj 1 -> Kf f16 row-major
//   proj 2 -> Vt f16 transposed: Vt[(b*1024+n)*2048+s]
// ---------------------------------------------------------------------------
__global__ __launch_bounds__(256) void qkv_gemm(const _Float16* __restrict__ Acat,
                                                const _Float16* __restrict__ Wt,
                                                _Float16* __restrict__ Qf,
                                                _Float16* __restrict__ Kf,
                                                _Float16* __restrict__ Vt) {
  __shared__ _Float16 lA[128 * 32];
  __shared__ _Float16 lB[128 * 32];
  int tid = threadIdx.x;
  int wave = tid >> 6, lane = tid & 63, quad = lane >> 4, l15 = lane & 15;
  int wgid = blockIdx.y * 8 + blockIdx.x;          // nwg = 1536
  int swz = (wgid & 7) * 192 + (wgid >> 3);        // bijective (1536 % 8 == 0)
  int bn = swz & 7, bm = swz >> 3;
  int proj = bm >> 6;
  int wm = wave >> 1, wn = wave & 1;

  const _Float16* A = Acat + (size_t)bm * 128 * 1024;
  const _Float16* W = Wt + (size_t)proj * 1024 * 1024;

  floatx4 fzero = {0.f, 0.f, 0.f, 0.f};
  floatx4 acc[4][4];
#pragma unroll
  for (int i = 0; i < 4; ++i)
#pragma unroll
    for (int j = 0; j < 4; ++j) acc[i][j] = fzero;

  int g0 = tid, g1 = 256 + tid;
  int row0 = g0 >> 2, gc0 = (g0 & 3) ^ ((row0 >> 1) & 3);
  int row1 = g1 >> 2, gc1 = (g1 & 3) ^ ((row1 >> 1) & 3);
  const _Float16* a0 = A + ((size_t)row0 * 1024 + gc0 * 8);
  const _Float16* a1 = A + ((size_t)row1 * 1024 + gc1 * 8);
  const _Float16* b0 = W + ((size_t)(bn * 128 + row0) * 1024 + gc0 * 8);
  const _Float16* b1 = W + ((size_t)(bn * 128 + row1) * 1024 + gc1 * 8);

  for (int k0 = 0; k0 < 1024; k0 += 32) {
    __builtin_amdgcn_global_load_lds((const GLOBAL_AS void*)(a0 + k0),
                                     (LDS_AS void*)(lA + g0 * 8), 16, 0, 0);
    __builtin_amdgcn_global_load_lds((const GLOBAL_AS void*)(a1 + k0),
                                     (LDS_AS void*)(lA + g1 * 8), 16, 0, 0);
    __builtin_amdgcn_global_load_lds((const GLOBAL_AS void*)(b0 + k0),
                                     (LDS_AS void*)(lB + g0 * 8), 16, 0, 0);
    __builtin_amdgcn_global_load_lds((const GLOBAL_AS void*)(b1 + k0),
                                     (LDS_AS void*)(lB + g1 * 8), 16, 0, 0);
    __syncthreads();

    half8 af[4], bf[4];
#pragma unroll
    for (int i = 0; i < 4; ++i) {
      int row = wm * 64 + i * 16 + l15;
      af[i] = *(const half8*)(lA + (row * 4 + (quad ^ ((row >> 1) & 3))) * 8);
    }
#pragma unroll
    for (int j = 0; j < 4; ++j) {
      int row = wn * 64 + j * 16 + l15;
      bf[j] = *(const half8*)(lB + (row * 4 + (quad ^ ((row >> 1) & 3))) * 8);
    }
#pragma unroll
    for (int i = 0; i < 4; ++i)
#pragma unroll
      for (int j = 0; j < 4; ++j)
        acc[i][j] = __builtin_amdgcn_mfma_f32_16x16x32_f16(af[i], bf[j], acc[i][j], 0, 0, 0);
    __syncthreads();
  }

  // ---- epilogue (block-uniform proj branch) ----
  int rloc = (bm & 63) * 128;  // row within this projection's [8192,1024] output
#pragma unroll
  for (int i = 0; i < 4; ++i) {
#pragma unroll
    for (int j = 0; j < 4; ++j) {
      int rowb = rloc + wm * 64 + i * 16 + quad * 4;
      int col = bn * 128 + wn * 64 + j * 16 + l15;
      if (proj == 0) {
#pragma unroll
        for (int r = 0; r < 4; ++r)
          Qf[(size_t)(rowb + r) * 1024 + col] = (_Float16)(acc[i][j][r] * QSCALE);
      } else if (proj == 1) {
#pragma unroll
        for (int r = 0; r < 4; ++r)
          Kf[(size_t)(rowb + r) * 1024 + col] = (_Float16)acc[i][j][r];
      } else {
        int b = rowb >> 11, s = rowb & 2047;
        half4v pk = {(_Float16)acc[i][j][0], (_Float16)acc[i][j][1],
                     (_Float16)acc[i][j][2], (_Float16)acc[i][j][3]};
        *(half4v*)(Vt + (size_t)(b * 1024 + col) * 2048 + s) = pk;
      }
    }
  }
}

// ---------------------------------------------------------------------------
// Final GEMM: d_out[8192,1024] = Of[8192,1024] @ Wo^T  (fp32 out)
// XCD-swizzled (nwg = 512, 512 % 8 == 0).
// ---------------------------------------------------------------------------
__global__ __launch_bounds__(256) void gemm_out(const _Float16* __restrict__ A,
                                                const _Float16* __restrict__ Wt,
                                                float* __restrict__ C) {
  __shared__ _Float16 lA[128 * 32];
  __shared__ _Float16 lB[128 * 32];
  int tid = threadIdx.x;
  int wave = tid >> 6, lane = tid & 63, quad = lane >> 4, l15 = lane & 15;
  int wgid = blockIdx.y * 8 + blockIdx.x;          // nwg = 512
  int swz = (wgid & 7) * 64 + (wgid >> 3);
  int bn = swz & 7, bm = swz >> 3;
  int wm = wave >> 1, wn = wave & 1;

  floatx4 fzero = {0.f, 0.f, 0.f, 0.f};
  floatx4 acc[4][4];
#pragma unroll
  for (int i = 0; i < 4; ++i)
#pragma unroll
    for (int j = 0; j < 4; ++j) acc[i][j] = fzero;

  int g0 = tid, g1 = 256 + tid;
  int row0 = g0 >> 2, gc0 = (g0 & 3) ^ ((row0 >> 1) & 3);
  int row1 = g1 >> 2, gc1 = (g1 & 3) ^ ((row1 >> 1) & 3);
  const _Float16* a0 = A + ((size_t)(bm * 128 + row0) * 1024 + gc0 * 8);
  const _Float16* a1 = A + ((size_t)(bm * 128 + row1) * 1024 + gc1 * 8);
  const _Float16* b0 = Wt + ((size_t)(bn * 128 + row0) * 1024 + gc0 * 8);
  const _Float16* b1 = Wt + ((size_t)(bn * 128 + row1) * 1024 + gc1 * 8);

  for (int k0 = 0; k0 < 1024; k0 += 32) {
    __builtin_amdgcn_global_load_lds((const GLOBAL_AS void*)(a0 + k0),
                                     (LDS_AS void*)(lA + g0 * 8), 16, 0, 0);
    __builtin_amdgcn_global_load_lds((const GLOBAL_AS void*)(a1 + k0),
                                     (LDS_AS void*)(lA + g1 * 8), 16, 0, 0);
    __builtin_amdgcn_global_load_lds((const GLOBAL_AS void*)(b0 + k0),
                                     (LDS_AS void*)(lB + g0 * 8), 16, 0, 0);
    __builtin_amdgcn_global_load_lds((const GLOBAL_AS void*)(b1 + k0),
                                     (LDS_AS void*)(lB + g1 * 8), 16, 0, 0);
    __syncthreads();

    half8 af[4], bf[4];
#pragma unroll
    for (int i = 0; i < 4; ++i) {
      int row = wm * 64 + i * 16 + l15;
      af[i] = *(const half8*)(lA + (row * 4 + (quad ^ ((row >> 1) & 3))) * 8);
    }
#pragma unroll
    for (int j = 0; j < 4; ++j) {
      int row = wn * 64 + j * 16 + l15;
      bf[j] = *(const half8*)(lB + (row * 4 + (quad ^ ((row >> 1) & 3))) * 8);
    }
#pragma unroll
    for (int i = 0; i < 4; ++i)
#pragma unroll
      for (int j = 0; j < 4; ++j)
        acc[i][j] = __builtin_amdgcn_mfma_f32_16x16x32_f16(af[i], bf[j], acc[i][j], 0, 0, 0);
    __syncthreads();
  }

#pragma unroll
  for (int i = 0; i < 4; ++i)
#pragma unroll
    for (int j = 0; j < 4; ++j) {
      int rowb = bm * 128 + wm * 64 + i * 16 + quad * 4;
      int col = bn * 128 + wn * 64 + j * 16 + l15;
#pragma unroll
      for (int r = 0; r < 4; ++r) C[(size_t)(rowb + r) * 1024 + col] = acc[i][j][r];
    }
}

// ---------------------------------------------------------------------------
// Flash attention, STATIC-MAX softmax, SWAPPED QK^T, T14 async-stage +
// LDS DOUBLE-BUFFER (one barrier per chunk).
// Per chunk: barrier (buf[cur] visible) -> issue next chunk's global loads
// into regs -> QK/softmax/PV from buf[cur] -> ds_write regs -> buf[cur^1].
// Writes to buf[cur^1] are ordered after the barrier, which follows every
// wave's reads of buf[cur^1] from the previous iteration -> race-free with
// a single barrier. Global-load latency hides under the compute phase.
// LDS = 2*8K (K) + 2*8K (V) + 8K (P) = 40KB -> 4 blocks/CU.
// grid (32, 64) block 256
// ---------------------------------------------------------------------------
__global__ __launch_bounds__(256) void attn_kernel(const _Float16* __restrict__ Q,
                                                   const _Float16* __restrict__ K,
                                                   const _Float16* __restrict__ Vt,
                                                   const int* __restrict__ vlens,
                                                   _Float16* __restrict__ O) {
  __shared__ _Float16 lK[2][64 * 64];   // [key][dh], swizzled, double-buffered
  __shared__ _Float16 lV[2][64 * 64];   // [dh][key], swizzled, double-buffered
  __shared__ _Float16 lP[4 * 16 * 64];  // per-wave [qrow][key], granule-swizzled

  int tid = threadIdx.x, wave = tid >> 6, lane = tid & 63, quad = lane >> 4, l15 = lane & 15;
  int bh = blockIdx.y, b = bh >> 4, h = bh & 15;
  int q0 = blockIdx.x * 64;
  int vlen = vlens[b];
  int nch = (vlen == 0) ? (SS / 64) : ((vlen + 63) >> 6);
  float mask_val = (vlen == 0) ? 0.0f : -1.0e6f;

  const _Float16* qb = Q + ((size_t)(b * SS + q0 + wave * 16 + l15) * DD + h * 64 + quad * 8);
  half8 qf0 = *(const half8*)qb;
  half8 qf1 = *(const half8*)(qb + 32);

  // ---- staging addresses (two slots per thread, kc-invariant bases) ----
  int ss0 = tid, ss1 = tid + 256;
  int srow0 = ss0 >> 3, sgc0 = ss0 & 7;
  int srow1 = ss1 >> 3, sgc1 = ss1 & 7;
  int sidx0 = (srow0 * 8 + (sgc0 ^ (srow0 & 7))) * 8;
  int sidx1 = (srow1 * 8 + (sgc1 ^ (srow1 & 7))) * 8;
  const _Float16* kp0 = K + ((size_t)(b * SS + srow0) * DD + h * 64 + sgc0 * 8);
  const _Float16* kp1 = K + ((size_t)(b * SS + srow1) * DD + h * 64 + sgc1 * 8);
  const _Float16* vp0 = Vt + ((size_t)(b * DD + h * 64 + srow0) * SS + sgc0 * 8);
  const _Float16* vp1 = Vt + ((size_t)(b * DD + h * 64 + srow1) * SS + sgc1 * 8);

  // ---- hoisted, kc-invariant LDS fragment offsets (halves) ----
  int off[2][4];  // lK / lV fragment reads (same swizzle both)
#pragma unroll
  for (int ks = 0; ks < 2; ++ks)
#pragma unroll
    for (int j = 0; j < 4; ++j) {
      int row = j * 16 + l15, gc = ks * 4 + quad;
      off[ks][j] = (row * 8 + (gc ^ (row & 7))) * 8;
    }
  int pbase = wave * 1024 + l15 * 64;
  int wp[4], rpl[2], rph[2];
#pragma unroll
  for (int j = 0; j < 4; ++j) wp[j] = pbase + (((j * 4 + quad) ^ l15) << 2);
#pragma unroll
  for (int ks = 0; ks < 2; ++ks) {
    int gl = ks * 8 + quad * 2;
    rpl[ks] = pbase + ((gl ^ l15) << 2);
    rph[ks] = pbase + (((gl + 1) ^ l15) << 2);
  }

  float l_acc = 0.f;
  floatx4 fzero = {0.f, 0.f, 0.f, 0.f};
  floatx4 o[4];
#pragma unroll
  for (int j = 0; j < 4; ++j) o[j] = fzero;

  // ---- prologue: chunk 0 -> regs -> buf0 ----
  half8 rk0 = *(const half8*)kp0;
  half8 rk1 = *(const half8*)kp1;
  half8 rv0 = *(const half8*)vp0;
  half8 rv1 = *(const half8*)vp1;
  *(half8*)(lK[0] + sidx0) = rk0;
  *(half8*)(lK[0] + sidx1) = rk1;
  *(half8*)(lV[0] + sidx0) = rv0;
  *(half8*)(lV[0] + sidx1) = rv1;
  int cur = 0;

  for (int kc = 0; kc < nch; ++kc) {
    __syncthreads();  // buf[cur] writes visible; prior reads of buf[cur^1] done

    // ---- issue next chunk's loads (clamped on last iter; latency hides) ----
    int kn = (kc + 1 < nch) ? kc + 1 : kc;
    size_t koff = (size_t)kn * 64 * DD;
    size_t voff = (size_t)kn * 64;
    rk0 = *(const half8*)(kp0 + koff);
    rk1 = *(const half8*)(kp1 + koff);
    rv0 = *(const half8*)(vp0 + voff);
    rv1 = *(const half8*)(vp1 + voff);

    const _Float16* cK = lK[cur];
    const _Float16* cV = lV[cur];
    int kb = kc * 64;

    // ---- S^T = K Q^T (64 keys x 16 queries per wave) ----
    floatx4 sacc[4];
#pragma unroll
    for (int j = 0; j < 4; ++j) sacc[j] = fzero;
    __builtin_amdgcn_s_setprio(1);
#pragma unroll
    for (int ks = 0; ks < 2; ++ks) {
      half8 qf = ks ? qf1 : qf0;
#pragma unroll
      for (int j = 0; j < 4; ++j) {
        half8 kf = *(const half8*)(cK + off[ks][j]);
        sacc[j] = __builtin_amdgcn_mfma_f32_16x16x32_f16(kf, qf, sacc[j], 0, 0, 0);
      }
    }
    __builtin_amdgcn_s_setprio(0);

    // ---- exp2 (mask branch is wave-uniform) ----
    float p[4][4];
    if (kb + 64 <= vlen) {
#pragma unroll
      for (int j = 0; j < 4; ++j)
#pragma unroll
        for (int r = 0; r < 4; ++r) p[j][r] = __builtin_amdgcn_exp2f(sacc[j][r]);
    } else {
#pragma unroll
      for (int j = 0; j < 4; ++j)
#pragma unroll
        for (int r = 0; r < 4; ++r) {
          int key = kb + j * 16 + quad * 4 + r;
          float s = (key < vlen) ? sacc[j][r] : mask_val;
          p[j][r] = __builtin_amdgcn_exp2f(s);
        }
    }

    // ---- row-sum + packed P write (b64 per j, keys contiguous in r) ----
#pragma unroll
    for (int j = 0; j < 4; ++j) {
      l_acc += (p[j][0] + p[j][1]) + (p[j][2] + p[j][3]);
      half2v lo = __builtin_bit_cast(half2v, __builtin_amdgcn_cvt_pkrtz(p[j][0], p[j][1]));
      half2v hi = __builtin_bit_cast(half2v, __builtin_amdgcn_cvt_pkrtz(p[j][2], p[j][3]));
      half4v w4 = {lo.x, lo.y, hi.x, hi.y};
      *(half4v*)(lP + wp[j]) = w4;
    }

    // ---- O += P V (in-wave lP write->read ordered by lgkmcnt) ----
    __builtin_amdgcn_s_setprio(1);
#pragma unroll
    for (int ks = 0; ks < 2; ++ks) {
      half4v plo = *(const half4v*)(lP + rpl[ks]);
      half4v phi = *(const half4v*)(lP + rph[ks]);
      half8 pf = {plo.x, plo.y, plo.z, plo.w, phi.x, phi.y, phi.z, phi.w};
#pragma unroll
      for (int j = 0; j < 4; ++j) {
        half8 vf = *(const half8*)(cV + off[ks][j]);
        o[j] = __builtin_amdgcn_mfma_f32_16x16x32_f16(pf, vf, o[j], 0, 0, 0);
      }
    }
    __builtin_amdgcn_s_setprio(0);

    // ---- write next chunk into the other buffer (no barrier needed) ----
    _Float16* nK = lK[cur ^ 1];
    _Float16* nV = lV[cur ^ 1];
    *(half8*)(nK + sidx0) = rk0;
    *(half8*)(nK + sidx1) = rk1;
    *(half8*)(nV + sidx0) = rv0;
    *(half8*)(nV + sidx1) = rv1;
    cur ^= 1;
  }

  // ---- epilogue: reduce l over quads, redistribute 1/l, write O ----
  float l = l_acc;
  l += __shfl_xor(l, 16);
  l += __shfl_xor(l, 32);
  float inv = 1.0f / l;
  float inv_r[4];
#pragma unroll
  for (int r = 0; r < 4; ++r) inv_r[r] = __shfl(inv, quad * 4 + r);
#pragma unroll
  for (int j = 0; j < 4; ++j) {
    int col = h * 64 + j * 16 + l15;
#pragma unroll
    for (int r = 0; r < 4; ++r) {
      int qrow = q0 + wave * 16 + quad * 4 + r;
      O[(size_t)(b * SS + qrow) * DD + col] = (_Float16)(o[j][r] * inv_r[r]);
    }
  }
}

// ---------------------------------------------------------------------------
extern "C" void kernel_launch(void* const* d_in, const int* in_sizes, int n_in,
                              void* d_out, int out_size, void* d_ws, size_t ws_size,
                              hipStream_t stream) {
  const float* q = (const float*)d_in[0];
  const float* k = (const float*)d_in[1];
  const float* v = (const float*)d_in[2];
  const int* vl = (const int*)d_in[3];
  const float* wq = (const float*)d_in[4];
  const float* wk = (const float*)d_in[5];
  const float* wv = (const float*)d_in[6];
  const float* wo = (const float*)d_in[7];

  char* ws = (char*)d_ws;
  _Float16* Wt = (_Float16*)ws;                        // 4 x 1M f16  = 8 MB
  _Float16* Acat = (_Float16*)(ws + (8u << 20));       // 48 MB [3 x 8192 x 1024]
  _Float16* Qf = (_Float16*)(ws + (56u << 20));        // 16 MB
  _Float16* Kf = (_Float16*)(ws + (72u << 20));        // 16 MB
  _Float16* Vt = (_Float16*)(ws + (88u << 20));        // 16 MB [B, D, S] (104 MB total)
  _Float16* Of = Acat;                                  // Acat dead after qkv_gemm

  dim3 blk(256);

  wt_kernel<<<dim3(32, 32, 4), blk, 0, stream>>>(wq, wk, wv, wo, Wt);
  cvt3_kernel<<<dim3(4096, 3), blk, 0, stream>>>(q, k, v, Acat);
  qkv_gemm<<<dim3(8, 192), blk, 0, stream>>>(Acat, Wt, Qf, Kf, Vt);
  attn_kernel<<<dim3(32, 64), blk, 0, stream>>>(Qf, Kf, Vt, vl, Of);
  gemm_out<<<dim3(8, 64), blk, 0, stream>>>(Of, Wt + (3u << 20), (float*)d_out);
}